// Round 12
// baseline (156.820 us; speedup 1.0000x reference)
//
#include <hip/hip_runtime.h>
#include <hip/hip_bf16.h>
#include <math.h>

#define N 1024
#define K 48
#define A 5
#define LOCALD 512
#define PAIRD 128
#define ROWS 32
#define TPB 3                // tiles per block (main): 512 blocks * 3 * 32 rows = 49152
#define MTPB 2               // tiles per block (mlp): 384 blocks * 2 * 64 rows = 49152
#define FEATK 544            // 34 * 16, zero-padded from 514
#define SF_STRIDE_B 1152     // 576 fp16 per row; multiple of 128 B for XOR swizzle

// ws float-offsets (LI/LJ kept at legacy offsets)
#define WS_LI (N*9 + N*3 + N*15)
#define WS_LJ (WS_LI + N*128)
// ws byte-offsets — [col][k] fp16 layouts (round-7 proven)
#define WCT_OFF 1159168u     // 128*544 fp16  (WcatT[col][k])
#define W1T_OFF 1298432u     // 256*128 fp16  (w1T[col][k])
#define W2T_OFF 1363968u     // 128*256 fp16  (w2T[col][k])
#define PA_OFF  1429504u     // 49152*128 fp16 post-LN activations (split mode)
#define WS_NEEDED (1429504ull + 49152ull*128*2)

typedef _Float16 half8 __attribute__((ext_vector_type(8)));
typedef float f32x16 __attribute__((ext_vector_type(16)));

// gelu(x) = 0.5x(1+tanh(u)) = x * sigmoid(2u),  u = 0.7978845608(x + 0.044715 x^3)
__device__ __forceinline__ float gelu_fast(float x) {
    float u2 = 1.5957691216057308f * x * (1.0f + 0.044715f * x * x);  // 2u
    float t = __expf(-u2);
    return x * __builtin_amdgcn_rcpf(1.0f + t);
}

// Build frame R (R[i*3+col], col0=e1,col1=e2,col2=e3) from P = [n, ca, c] (9 floats)
__device__ __forceinline__ void frame_from(const float* __restrict__ P, float* __restrict__ R) {
    float e1x = P[6] - P[3], e1y = P[7] - P[4], e1z = P[8] - P[5];
    float inv1 = rsqrtf(e1x * e1x + e1y * e1y + e1z * e1z + 1e-8f);
    e1x *= inv1; e1y *= inv1; e1z *= inv1;
    float v2x = P[0] - P[3], v2y = P[1] - P[4], v2z = P[2] - P[5];
    float dp = v2x * e1x + v2y * e1y + v2z * e1z;
    float e2x = v2x - dp * e1x, e2y = v2y - dp * e1y, e2z = v2z - dp * e1z;
    float inv2 = rsqrtf(e2x * e2x + e2y * e2y + e2z * e2z + 1e-8f);
    e2x *= inv2; e2y *= inv2; e2z *= inv2;
    float e3x = e1y * e2z - e1z * e2y;
    float e3y = e1z * e2x - e1x * e2z;
    float e3z = e1x * e2y - e1y * e2x;
    R[0] = e1x; R[1] = e2x; R[2] = e3x;
    R[3] = e1y; R[4] = e2y; R[5] = e3y;
    R[6] = e1z; R[7] = e2z; R[8] = e3z;
}

// prep (blocks 0..255, 4 rows each): li/lj projections.
// convw (blocks 256..783): fp16 weight transpose, coalesced reads.
__global__ __launch_bounds__(256) void prep_kernel(
    const float* __restrict__ local_,
    const float* __restrict__ W_li, const float* __restrict__ W_lj,
    const float* __restrict__ Wd, const float* __restrict__ Wdir,
    const float* __restrict__ Wrot, const float* __restrict__ Wv,
    const float* __restrict__ w1, const float* __restrict__ w2,
    float* __restrict__ ws, char* __restrict__ wsb)
{
    const int tid = threadIdx.x;
    if (blockIdx.x >= 256) {
        _Float16* wct = (_Float16*)(wsb + WCT_OFF);
        _Float16* w1t = (_Float16*)(wsb + W1T_OFF);
        _Float16* w2t = (_Float16*)(wsb + W2T_OFF);
        int g = (blockIdx.x - 256) * 256 + tid;
        if (g < 128 * 544) {
            int c = g & 127, f = g >> 7;            // read coalesced over c
            float v = 0.0f;
            if (f < 400) v = Wd[(size_t)f * 128 + c];
            else if (f < 475) v = Wdir[(size_t)(f - 400) * 128 + c];
            else if (f < 484) v = Wrot[(size_t)(f - 475) * 128 + c];
            else if (f < 514) v = Wv[(size_t)(f - 484) * 128 + c];
            wct[(size_t)c * FEATK + f] = (_Float16)v;
        } else {
            int g2 = g - 128 * 544;
            if (g2 < 256 * 128) {
                int c = g2 & 255, f = g2 >> 8;      // read w1 coalesced
                w1t[(size_t)c * 128 + f] = (_Float16)w1[(size_t)f * 256 + c];
            } else {
                int g3 = g2 - 256 * 128;
                if (g3 < 128 * 256) {
                    int c = g3 & 127, f = g3 >> 7;  // read w2 coalesced
                    w2t[(size_t)c * 256 + f] = (_Float16)w2[(size_t)f * 128 + c];
                }
            }
        }
        return;
    }

    const int n0 = blockIdx.x * 4;
    __shared__ float sl[4][LOCALD];
    for (int t = tid; t < 4 * LOCALD; t += 256) {
        int r = t >> 9, q = t & 511;
        sl[r][q] = local_[(size_t)(n0 + r) * LOCALD + q];
    }
    __syncthreads();

    const int c = tid & 127;
    const int hh = tid >> 7;
    const int r0 = hh * 2;
    float ali0 = 0, ali1 = 0, alj0 = 0, alj1 = 0;
    const float* wli = W_li + c;
    const float* wlj = W_lj + c;
    #pragma unroll 8
    for (int f = 0; f < LOCALD; ++f) {
        float a_ = wli[(size_t)f * 128];
        float b_ = wlj[(size_t)f * 128];
        float l0 = sl[r0 + 0][f], l1 = sl[r0 + 1][f];
        ali0 += l0 * a_; ali1 += l1 * a_;
        alj0 += l0 * b_; alj1 += l1 * b_;
    }
    ws[WS_LI + (size_t)(n0 + r0 + 0) * 128 + c] = ali0;
    ws[WS_LI + (size_t)(n0 + r0 + 1) * 128 + c] = ali1;
    ws[WS_LJ + (size_t)(n0 + r0 + 0) * 128 + c] = alj0;
    ws[WS_LJ + (size_t)(n0 + r0 + 1) * 128 + c] = alj1;
}

// swizzled fp16 LDS store into feature buffer
__device__ __forceinline__ void sfw(char* smem, int r, int f, float v) {
    int off = r * SF_STRIDE_B + ((f * 2) ^ ((r & 7) << 4));
    *(_Float16*)(smem + off) = (_Float16)v;
}

// SPLIT=true: ends after LN, writes fp16 pA to global (vectorized); MLP in mlp_kernel.
// Multi-tile: B-fragments (bw[34]) register-resident across TPB tiles.
template<bool SPLIT>
__global__ __launch_bounds__(256, 2) void main_kernel(
    const float* __restrict__ pair, const float* __restrict__ pos,
    const int* __restrict__ neigh, const int* __restrict__ mask,
    const float* __restrict__ ln_s, const float* __restrict__ ln_b,
    const float* __restrict__ b1, const float* __restrict__ b2,
    const float* __restrict__ ws, const char* __restrict__ wsb,
    _Float16* __restrict__ pa, float* __restrict__ out)
{
    const int tid = threadIdx.x;
    const int lane = tid & 63;
    const int wv = tid >> 6;
    const int myrow = lane & 31;
    const int hi = lane >> 5;
    const int khalf = hi * 8;
    const int swz = (myrow & 7) << 4;

    __shared__ __align__(16) char smem[40960];
    int*   sn  = (int*)(smem + 36864);
    int*   sj  = (int*)(smem + 36992);
    float* spn = (float*)(smem + 37120);   // [32][15]
    float* spj = (float*)(smem + 39040);   // [32][15]

    const int colbase = wv * 32 + myrow;

    // ---- B fragments for GEMM1: loaded ONCE per block, reused across TPB tiles ----
    half8 bw[34];
    {
        const _Float16* wp = (const _Float16*)(wsb + WCT_OFF) + (size_t)colbase * FEATK + khalf;
        #pragma unroll
        for (int ks = 0; ks < 34; ++ks)
            bw[ks] = *(const half8*)(wp + ks * 16);
    }

    for (int tile = 0; tile < TPB; ++tile) {
        const int R0 = (blockIdx.x * TPB + tile) * ROWS;
        __syncthreads();   // protect smem reuse across tiles (no-op cost on tile 0)

        if (tid < ROWS) {
            int Rg = R0 + tid;
            int n = Rg / K;
            int kk = Rg - n * K;
            int j = neigh[n * K + kk];
            if (j < 0) j += N;
            sn[tid] = n; sj[tid] = j;
        }
        __syncthreads();

        // ---- prefetch pair + li + lj into pv (r9 phase order) ----
        const int nb0 = R0 / K;
        const int nb1 = (nb0 + 1 < N) ? nb0 + 1 : nb0;
        float li0 = ws[WS_LI + (size_t)nb0 * PAIRD + colbase];
        float li1 = ws[WS_LI + (size_t)nb1 * PAIRD + colbase];
        float pv[16];
        #pragma unroll
        for (int q = 0; q < 16; ++q) {
            int rr = (q & 3) + 8 * (q >> 2) + 4 * hi;
            int nq = sn[rr], jq = sj[rr];
            float li = (nq == nb0) ? li0 : li1;
            pv[q] = pair[((size_t)nq * N + jq) * PAIRD + colbase]
                  + ws[WS_LJ + (size_t)jq * PAIRD + colbase] + li;
        }

        for (int t = tid; t < ROWS * 15; t += 256) {
            int r = t / 15, q = t % 15;
            spn[t] = pos[(size_t)sn[r] * 15 + q];
            spj[t] = pos[(size_t)sj[r] * 15 + q];
        }
        __syncthreads();

        // ===== feature generation: 8 threads per row =====
        {
            const int fr  = tid >> 3;
            const int sub = tid & 7;
            const float* Pn = spn + fr * 15;
            const float* Pj = spj + fr * 15;

            sfw(smem, fr, 514 + sub, 0.0f);
            sfw(smem, fr, 522 + sub, 0.0f);
            sfw(smem, fr, 530 + sub, 0.0f);
            if (sub < 6) sfw(smem, fr, 538 + sub, 0.0f);

            float rn[9];
            frame_from(Pn, rn);

            #pragma unroll
            for (int m = 0; m < 4; ++m) {
                int ab = sub + 8 * m;
                if (ab < 25) {
                    int a = ab / 5, b = ab - 5 * (ab / 5);
                    float o0 = Pn[a * 3 + 0] - Pj[b * 3 + 0];
                    float o1 = Pn[a * 3 + 1] - Pj[b * 3 + 1];
                    float o2 = Pn[a * 3 + 2] - Pj[b * 3 + 2];
                    float d = sqrtf(o0 * o0 + o1 * o1 + o2 * o2 + 1e-8f);
                    float z = d * (16.0f / 22.0f);
                    int base = a * 80 + b * 16;
                    int rb = fr * SF_STRIDE_B;
                    int rsw = (fr & 7) << 4;
                    #pragma unroll
                    for (int bp = 0; bp < 8; ++bp) {
                        float e0 = __expf(-z * z);
                        float z1 = z - 1.0666666666666667f;
                        float e1 = __expf(-z1 * z1);
                        z = z1 - 1.0666666666666667f;
                        union { _Float16 h[2]; unsigned u; } pk;
                        pk.h[0] = (_Float16)e0; pk.h[1] = (_Float16)e1;
                        int off = rb + (((base + bp * 2) * 2) ^ rsw);
                        *(unsigned*)(smem + off) = pk.u;
                    }
                    float l0 = rn[0] * o0 + rn[3] * o1 + rn[6] * o2;
                    float l1 = rn[1] * o0 + rn[4] * o1 + rn[7] * o2;
                    float l2 = rn[2] * o0 + rn[5] * o1 + rn[8] * o2;
                    float inv = rsqrtf(l0 * l0 + l1 * l1 + l2 * l2 + 1e-8f);
                    int dbase = 400 + a * 15 + b * 3;
                    sfw(smem, fr, dbase + 0, l0 * inv);
                    sfw(smem, fr, dbase + 1, l1 * inv);
                    sfw(smem, fr, dbase + 2, l2 * inv);
                }
            }

            #pragma unroll
            for (int m = 0; m < 2; ++m) {
                int task = (m == 0) ? sub : (sub < 2 ? 8 + sub : -1);
                if (task >= 0) {
                    int a = task >> 1;
                    int kind = task & 1;
                    const float* Ps = kind ? Pj : Pn;
                    float v0 = Ps[a * 3 + 0] - Pn[3];
                    float v1 = Ps[a * 3 + 1] - Pn[4];
                    float v2 = Ps[a * 3 + 2] - Pn[5];
                    float x0 = rn[0] * v0 + rn[3] * v1 + rn[6] * v2;
                    float x1 = rn[1] * v0 + rn[4] * v1 + rn[7] * v2;
                    float x2 = rn[2] * v0 + rn[5] * v1 + rn[8] * v2;
                    int dbase = 484 + a * 6 + kind * 3;
                    sfw(smem, fr, dbase + 0, 0.1f * x0);
                    sfw(smem, fr, dbase + 1, 0.1f * x1);
                    sfw(smem, fr, dbase + 2, 0.1f * x2);
                }
            }

            if (sub == 7) {
                float rj[9];
                frame_from(Pj, rj);
                #pragma unroll
                for (int i = 0; i < 3; ++i)
                    #pragma unroll
                    for (int jd = 0; jd < 3; ++jd) {
                        float v = rn[0 * 3 + i] * rj[0 * 3 + jd]
                                + rn[1 * 3 + i] * rj[1 * 3 + jd]
                                + rn[2 * 3 + i] * rj[2 * 3 + jd];
                        sfw(smem, fr, 475 + i * 3 + jd, v);
                    }
            }
        }
        __syncthreads();

        // ---- GEMM1: feat[32 x 544] @ Wcat[544 x 128]; B register-resident ----
        f32x16 acc0, acc1;
        #pragma unroll
        for (int q = 0; q < 16; ++q) { acc0[q] = 0.0f; acc1[q] = 0.0f; }
        #pragma unroll
        for (int ks = 0; ks < 34; ks += 2) {
            int k0 = ks * 16 + khalf;
            int k1 = (ks + 1) * 16 + khalf;
            half8 a0 = *(const half8*)(smem + myrow * SF_STRIDE_B + ((k0 * 2) ^ swz));
            half8 a1 = *(const half8*)(smem + myrow * SF_STRIDE_B + ((k1 * 2) ^ swz));
            acc0 = __builtin_amdgcn_mfma_f32_32x32x16_f16(a0, bw[ks], acc0, 0, 0, 0);
            acc1 = __builtin_amdgcn_mfma_f32_32x32x16_f16(a1, bw[ks + 1], acc1, 0, 0, 0);
        }
        __syncthreads();   // sfeat dead; smem[0:16K) becomes pbuf (fp32 [32][128])

        // ---- epilogue: acc + prefetched (pair+li+lj) -> pbuf ----
        #pragma unroll
        for (int q = 0; q < 16; ++q) {
            int rr = (q & 3) + 8 * (q >> 2) + 4 * hi;
            *(float*)(smem + rr * 512 + colbase * 4) = acc0[q] + acc1[q] + pv[q];
        }
        __syncthreads();

        // ---- LayerNorm ----
        {
            float lns0 = ln_s[lane], lns1 = ln_s[lane + 64];
            float lnb0 = ln_b[lane], lnb1 = ln_b[lane + 64];
            #pragma unroll
            for (int rr8 = 0; rr8 < 8; ++rr8) {
                int row = wv * 8 + rr8;
                float v0 = *(float*)(smem + row * 512 + lane * 4);
                float v1 = *(float*)(smem + row * 512 + (lane + 64) * 4);
                float s = v0 + v1, s2 = v0 * v0 + v1 * v1;
                #pragma unroll
                for (int o = 32; o > 0; o >>= 1) {
                    s += __shfl_xor(s, o, 64);
                    s2 += __shfl_xor(s2, o, 64);
                }
                float mu = s * (1.0f / 128.0f);
                float var = s2 * (1.0f / 128.0f) - mu * mu;
                float rs = rsqrtf(var + 1e-5f);
                float y0 = (v0 - mu) * rs * lns0 + lnb0;
                float y1 = (v1 - mu) * rs * lns1 + lnb1;
                if constexpr (SPLIT) {
                    // linear fp16 staging in LDS @16384; vectorized global store below
                    *(_Float16*)(smem + 16384 + row * 256 + lane * 2) = (_Float16)y0;
                    *(_Float16*)(smem + 16384 + row * 256 + (lane + 64) * 2) = (_Float16)y1;
                } else {
                    int sw = (row & 7) << 4;
                    *(_Float16*)(smem + 16384 + row * 256 + ((lane * 2) ^ sw)) = (_Float16)y0;
                    *(_Float16*)(smem + 16384 + row * 256 + (((lane + 64) * 2) ^ sw)) = (_Float16)y1;
                }
            }
        }
        __syncthreads();

        if constexpr (SPLIT) {
            // vectorized 16B/lane coalesced pa store
            for (int ch = tid; ch < ROWS * 16; ch += 256) {
                int row = ch >> 4, c16 = ch & 15;
                half8 v = *(const half8*)(smem + 16384 + row * 256 + c16 * 16);
                *(half8*)(pa + (size_t)(R0 + row) * PAIRD + c16 * 8) = v;
            }
            continue;   // next tile
        }

        // ---- MLP1 (fused mode) ----
        {
            const _Float16* w1t = (const _Float16*)(wsb + W1T_OFF);
            const int c0 = wv * 64 + myrow;
            const int c1 = c0 + 32;
            const _Float16* wp0 = w1t + (size_t)c0 * 128 + khalf;
            const _Float16* wp1 = w1t + (size_t)c1 * 128 + khalf;
            f32x16 h0, h1;
            #pragma unroll
            for (int q = 0; q < 16; ++q) { h0[q] = 0.0f; h1[q] = 0.0f; }
            #pragma unroll
            for (int ks = 0; ks < 8; ++ks) {
                half8 wf0 = *(const half8*)(wp0 + ks * 16);
                half8 wf1 = *(const half8*)(wp1 + ks * 16);
                int k0 = ks * 16 + khalf;
                half8 a = *(const half8*)(smem + 16384 + myrow * 256 + ((k0 * 2) ^ swz));
                h0 = __builtin_amdgcn_mfma_f32_32x32x16_f16(a, wf0, h0, 0, 0, 0);
                h1 = __builtin_amdgcn_mfma_f32_32x32x16_f16(a, wf1, h1, 0, 0, 0);
            }
            float bb0 = b1[c0], bb1 = b1[c1];
            #pragma unroll
            for (int q = 0; q < 16; ++q) {
                int rr = (q & 3) + 8 * (q >> 2) + 4 * hi;
                int sw = (rr & 7) << 4;
                *(_Float16*)(smem + rr * 512 + ((c0 * 2) ^ sw)) = (_Float16)gelu_fast(h0[q] + bb0);
                *(_Float16*)(smem + rr * 512 + ((c1 * 2) ^ sw)) = (_Float16)gelu_fast(h1[q] + bb1);
            }
        }
        __syncthreads();

        // ---- MLP2 (fused mode) ----
        {
            const _Float16* w2t = (const _Float16*)(wsb + W2T_OFF);
            const int oc = wv * 32 + myrow;
            const _Float16* wp = w2t + (size_t)oc * 256 + khalf;
            f32x16 o0, o1;
            #pragma unroll
            for (int q = 0; q < 16; ++q) { o0[q] = 0.0f; o1[q] = 0.0f; }
            #pragma unroll
            for (int ks = 0; ks < 16; ks += 2) {
                half8 w0 = *(const half8*)(wp + ks * 16);
                half8 w1f = *(const half8*)(wp + (ks + 1) * 16);
                int k0 = ks * 16 + khalf;
                int k1 = (ks + 1) * 16 + khalf;
                half8 a0 = *(const half8*)(smem + myrow * 512 + ((k0 * 2) ^ swz));
                half8 a1 = *(const half8*)(smem + myrow * 512 + ((k1 * 2) ^ swz));
                o0 = __builtin_amdgcn_mfma_f32_32x32x16_f16(a0, w0, o0, 0, 0, 0);
                o1 = __builtin_amdgcn_mfma_f32_32x32x16_f16(a1, w1f, o1, 0, 0, 0);
            }
            float bb = b2[oc];
            #pragma unroll
            for (int q = 0; q < 16; ++q) {
                int rr = (q & 3) + 8 * (q >> 2) + 4 * hi;
                out[((size_t)(R0 + rr)) * PAIRD + oc] = o0[q] + o1[q] + bb;
            }
        }

        if (tid < ROWS) {
            int Rg = R0 + tid;
            int n = Rg / K;
            int kk = Rg - n * K;
            int jr = neigh[n * K + kk];
            int jj = jr < 0 ? jr + N : jr;
            bool pm = (jr != -1) && (mask[n] != 0) && (mask[jj] != 0);
            out[(size_t)N * K * PAIRD + Rg] = pm ? 1.0f : 0.0f;
        }
    }  // tile loop
}

// MLP kernel (split mode): MTPB tiles of 64 rows per block; weights register-resident.
__global__ __launch_bounds__(256, 2) void mlp_kernel(
    const _Float16* __restrict__ pa, const int* __restrict__ neigh,
    const int* __restrict__ mask, const float* __restrict__ b1,
    const float* __restrict__ b2, const char* __restrict__ wsb,
    float* __restrict__ out)
{
    const int tid = threadIdx.x;
    const int lane = tid & 63;
    const int wv = tid >> 6;
    const int myrow = lane & 31;
    const int hi = lane >> 5;
    const int khalf = hi * 8;
    const int swz = (myrow & 7) << 4;

    __shared__ __align__(16) char smem[49152];  // pA [64][256B] @0, hbuf [64][512B] @16384

    // ---- weights: loaded once per block, reused across MTPB tiles ----
    const int c0 = wv * 64 + myrow;
    const int c1 = c0 + 32;
    const int oc = wv * 32 + myrow;
    half8 wf0[8], wf1[8], w2f[16];
    {
        const _Float16* w1t = (const _Float16*)(wsb + W1T_OFF);
        const _Float16* w2t = (const _Float16*)(wsb + W2T_OFF);
        const _Float16* wp0 = w1t + (size_t)c0 * 128 + khalf;
        const _Float16* wp1 = w1t + (size_t)c1 * 128 + khalf;
        const _Float16* wp2 = w2t + (size_t)oc * 256 + khalf;
        #pragma unroll
        for (int ks = 0; ks < 8; ++ks) {
            wf0[ks] = *(const half8*)(wp0 + ks * 16);
            wf1[ks] = *(const half8*)(wp1 + ks * 16);
        }
        #pragma unroll
        for (int ks = 0; ks < 16; ++ks)
            w2f[ks] = *(const half8*)(wp2 + ks * 16);
    }
    const float bb0 = b1[c0], bb1 = b1[c1], bb2 = b2[oc];

    for (int tile = 0; tile < MTPB; ++tile) {
        const int R0 = (blockIdx.x * MTPB + tile) * 64;
        __syncthreads();   // smem reuse guard

        for (int ch = tid; ch < 1024; ch += 256) {
            int row = ch >> 4, c16 = ch & 15;
            half8 v = *(const half8*)(pa + (size_t)(R0 + row) * PAIRD + c16 * 8);
            *(half8*)(smem + row * 256 + ((c16 * 16) ^ ((row & 7) << 4))) = v;
        }
        __syncthreads();

        // ---- MLP1: [64x128] @ w1[128x256] ----
        {
            f32x16 h00, h01, h10, h11;
            #pragma unroll
            for (int q = 0; q < 16; ++q) { h00[q] = 0.0f; h01[q] = 0.0f; h10[q] = 0.0f; h11[q] = 0.0f; }
            #pragma unroll
            for (int ks = 0; ks < 8; ++ks) {
                int k0 = ks * 16 + khalf;
                half8 a0 = *(const half8*)(smem + myrow * 256 + ((k0 * 2) ^ swz));
                half8 a1 = *(const half8*)(smem + (32 + myrow) * 256 + ((k0 * 2) ^ swz));
                h00 = __builtin_amdgcn_mfma_f32_32x32x16_f16(a0, wf0[ks], h00, 0, 0, 0);
                h01 = __builtin_amdgcn_mfma_f32_32x32x16_f16(a0, wf1[ks], h01, 0, 0, 0);
                h10 = __builtin_amdgcn_mfma_f32_32x32x16_f16(a1, wf0[ks], h10, 0, 0, 0);
                h11 = __builtin_amdgcn_mfma_f32_32x32x16_f16(a1, wf1[ks], h11, 0, 0, 0);
            }
            #pragma unroll
            for (int q = 0; q < 16; ++q) {
                int rr = (q & 3) + 8 * (q >> 2) + 4 * hi;
                int sw = (rr & 7) << 4;
                *(_Float16*)(smem + 16384 + rr * 512 + ((c0 * 2) ^ sw)) = (_Float16)gelu_fast(h00[q] + bb0);
                *(_Float16*)(smem + 16384 + rr * 512 + ((c1 * 2) ^ sw)) = (_Float16)gelu_fast(h01[q] + bb1);
                *(_Float16*)(smem + 16384 + (rr + 32) * 512 + ((c0 * 2) ^ sw)) = (_Float16)gelu_fast(h10[q] + bb0);
                *(_Float16*)(smem + 16384 + (rr + 32) * 512 + ((c1 * 2) ^ sw)) = (_Float16)gelu_fast(h11[q] + bb1);
            }
        }
        __syncthreads();

        // ---- MLP2: [64x256] @ w2[256x128] ----
        {
            f32x16 o0, o1;
            #pragma unroll
            for (int q = 0; q < 16; ++q) { o0[q] = 0.0f; o1[q] = 0.0f; }
            #pragma unroll
            for (int ks = 0; ks < 16; ++ks) {
                int k0 = ks * 16 + khalf;
                half8 a0 = *(const half8*)(smem + 16384 + myrow * 512 + ((k0 * 2) ^ swz));
                half8 a1 = *(const half8*)(smem + 16384 + (32 + myrow) * 512 + ((k0 * 2) ^ swz));
                o0 = __builtin_amdgcn_mfma_f32_32x32x16_f16(a0, w2f[ks], o0, 0, 0, 0);
                o1 = __builtin_amdgcn_mfma_f32_32x32x16_f16(a1, w2f[ks], o1, 0, 0, 0);
            }
            #pragma unroll
            for (int q = 0; q < 16; ++q) {
                int rr = (q & 3) + 8 * (q >> 2) + 4 * hi;
                out[((size_t)(R0 + rr)) * PAIRD + oc]      = o0[q] + bb2;
                out[((size_t)(R0 + rr + 32)) * PAIRD + oc] = o1[q] + bb2;
            }
        }

        if (tid < 64) {
            int Rg = R0 + tid;
            int n = Rg / K;
            int kk = Rg - n * K;
            int jr = neigh[n * K + kk];
            int jj = jr < 0 ? jr + N : jr;
            bool pm = (jr != -1) && (mask[n] != 0) && (mask[jj] != 0);
            out[(size_t)N * K * PAIRD + Rg] = pm ? 1.0f : 0.0f;
        }
    }  // tile loop
}

extern "C" void kernel_launch(void* const* d_in, const int* in_sizes, int n_in,
                              void* d_out, int out_size, void* d_ws, size_t ws_size,
                              hipStream_t stream) {
    const float* local_ = (const float*)d_in[0];
    const float* pos = (const float*)d_in[1];
    const float* pair = (const float*)d_in[2];
    const int* neigh = (const int*)d_in[3];
    const int* mask = (const int*)d_in[4];
    const float* W_li = (const float*)d_in[5];
    const float* W_lj = (const float*)d_in[6];
    const float* W_dist = (const float*)d_in[7];
    const float* W_dir = (const float*)d_in[8];
    const float* W_rot = (const float*)d_in[9];
    const float* W_vec = (const float*)d_in[10];
    const float* ln_s = (const float*)d_in[11];
    const float* ln_b = (const float*)d_in[12];
    const float* w1 = (const float*)d_in[13];
    const float* b1 = (const float*)d_in[14];
    const float* w2 = (const float*)d_in[15];
    const float* b2 = (const float*)d_in[16];
    float* ws = (float*)d_ws;
    char* wsb = (char*)d_ws;
    _Float16* pa = (_Float16*)(wsb + PA_OFF);
    float* out = (float*)d_out;

    hipLaunchKernelGGL(prep_kernel, dim3(256 + 528), dim3(256), 0, stream,
                       local_, W_li, W_lj, W_dist, W_dir, W_rot, W_vec,
                       w1, w2, ws, wsb);
    if (ws_size >= WS_NEEDED) {
        main_kernel<true><<<dim3((N * K) / (ROWS * TPB)), dim3(256), 0, stream>>>(
            pair, pos, neigh, mask, ln_s, ln_b, b1, b2, ws, wsb, pa, out);
        mlp_kernel<<<dim3((N * K) / (64 * MTPB)), dim3(256), 0, stream>>>(
            pa, neigh, mask, b1, b2, wsb, out);
    } else {
        main_kernel<false><<<dim3((N * K) / (ROWS * TPB)), dim3(256), 0, stream>>>(
            pair, pos, neigh, mask, ln_s, ln_b, b1, b2, ws, wsb, pa, out);
    }
}

// Round 13
// 79.716 us; speedup vs baseline: 1.9672x; 1.9672x over previous
//
#include <hip/hip_runtime.h>
#include <hip/hip_bf16.h>
#include <math.h>

#define N 1024
#define K 48
#define A 5
#define LOCALD 512
#define PAIRD 128
#define ROWS 32
#define FEATK 544            // 34 * 16, zero-padded from 514
#define SF_STRIDE_B 1152     // 576 fp16 per row; multiple of 128 B for XOR swizzle

// ws float-offsets (LI/LJ kept at legacy offsets)
#define WS_LI (N*9 + N*3 + N*15)
#define WS_LJ (WS_LI + N*128)
// ws byte-offsets — [col][k] fp16 layouts (round-7 proven)
#define WCT_OFF 1159168u     // 128*544 fp16  (WcatT[col][k])
#define W1T_OFF 1298432u     // 256*128 fp16  (w1T[col][k])
#define W2T_OFF 1363968u     // 128*256 fp16  (w2T[col][k])
#define PA_OFF  1429504u     // 49152*128 fp16 post-LN activations (split mode)
#define WS_NEEDED (1429504ull + 49152ull*128*2)

typedef _Float16 half8 __attribute__((ext_vector_type(8)));
typedef float f32x16 __attribute__((ext_vector_type(16)));

// gelu(x) = 0.5x(1+tanh(u)) = x * sigmoid(2u),  u = 0.7978845608(x + 0.044715 x^3)
__device__ __forceinline__ float gelu_fast(float x) {
    float u2 = 1.5957691216057308f * x * (1.0f + 0.044715f * x * x);  // 2u
    float t = __expf(-u2);
    return x * __builtin_amdgcn_rcpf(1.0f + t);
}

// Build frame R (R[i*3+col], col0=e1,col1=e2,col2=e3) from P = [n, ca, c] (9 floats)
__device__ __forceinline__ void frame_from(const float* __restrict__ P, float* __restrict__ R) {
    float e1x = P[6] - P[3], e1y = P[7] - P[4], e1z = P[8] - P[5];
    float inv1 = rsqrtf(e1x * e1x + e1y * e1y + e1z * e1z + 1e-8f);
    e1x *= inv1; e1y *= inv1; e1z *= inv1;
    float v2x = P[0] - P[3], v2y = P[1] - P[4], v2z = P[2] - P[5];
    float dp = v2x * e1x + v2y * e1y + v2z * e1z;
    float e2x = v2x - dp * e1x, e2y = v2y - dp * e1y, e2z = v2z - dp * e1z;
    float inv2 = rsqrtf(e2x * e2x + e2y * e2y + e2z * e2z + 1e-8f);
    e2x *= inv2; e2y *= inv2; e2z *= inv2;
    float e3x = e1y * e2z - e1z * e2y;
    float e3y = e1z * e2x - e1x * e2z;
    float e3z = e1x * e2y - e1y * e2x;
    R[0] = e1x; R[1] = e2x; R[2] = e3x;
    R[3] = e1y; R[4] = e2y; R[5] = e3y;
    R[6] = e1z; R[7] = e2z; R[8] = e3z;
}

// prep (blocks 0..255, 4 rows each): li/lj projections.
// convw (blocks 256..783): fp16 weight transpose, coalesced reads. [round-7 exact]
__global__ __launch_bounds__(256) void prep_kernel(
    const float* __restrict__ local_,
    const float* __restrict__ W_li, const float* __restrict__ W_lj,
    const float* __restrict__ Wd, const float* __restrict__ Wdir,
    const float* __restrict__ Wrot, const float* __restrict__ Wv,
    const float* __restrict__ w1, const float* __restrict__ w2,
    float* __restrict__ ws, char* __restrict__ wsb)
{
    const int tid = threadIdx.x;
    if (blockIdx.x >= 256) {
        _Float16* wct = (_Float16*)(wsb + WCT_OFF);
        _Float16* w1t = (_Float16*)(wsb + W1T_OFF);
        _Float16* w2t = (_Float16*)(wsb + W2T_OFF);
        int g = (blockIdx.x - 256) * 256 + tid;
        if (g < 128 * 544) {
            int c = g & 127, f = g >> 7;            // read coalesced over c
            float v = 0.0f;
            if (f < 400) v = Wd[(size_t)f * 128 + c];
            else if (f < 475) v = Wdir[(size_t)(f - 400) * 128 + c];
            else if (f < 484) v = Wrot[(size_t)(f - 475) * 128 + c];
            else if (f < 514) v = Wv[(size_t)(f - 484) * 128 + c];
            wct[(size_t)c * FEATK + f] = (_Float16)v;
        } else {
            int g2 = g - 128 * 544;
            if (g2 < 256 * 128) {
                int c = g2 & 255, f = g2 >> 8;      // read w1 coalesced
                w1t[(size_t)c * 128 + f] = (_Float16)w1[(size_t)f * 256 + c];
            } else {
                int g3 = g2 - 256 * 128;
                if (g3 < 128 * 256) {
                    int c = g3 & 127, f = g3 >> 7;  // read w2 coalesced
                    w2t[(size_t)c * 256 + f] = (_Float16)w2[(size_t)f * 128 + c];
                }
            }
        }
        return;
    }

    const int n0 = blockIdx.x * 4;
    __shared__ float sl[4][LOCALD];
    for (int t = tid; t < 4 * LOCALD; t += 256) {
        int r = t >> 9, q = t & 511;
        sl[r][q] = local_[(size_t)(n0 + r) * LOCALD + q];
    }
    __syncthreads();

    const int c = tid & 127;
    const int hh = tid >> 7;
    const int r0 = hh * 2;
    float ali0 = 0, ali1 = 0, alj0 = 0, alj1 = 0;
    const float* wli = W_li + c;
    const float* wlj = W_lj + c;
    #pragma unroll 8
    for (int f = 0; f < LOCALD; ++f) {
        float a_ = wli[(size_t)f * 128];
        float b_ = wlj[(size_t)f * 128];
        float l0 = sl[r0 + 0][f], l1 = sl[r0 + 1][f];
        ali0 += l0 * a_; ali1 += l1 * a_;
        alj0 += l0 * b_; alj1 += l1 * b_;
    }
    ws[WS_LI + (size_t)(n0 + r0 + 0) * 128 + c] = ali0;
    ws[WS_LI + (size_t)(n0 + r0 + 1) * 128 + c] = ali1;
    ws[WS_LJ + (size_t)(n0 + r0 + 0) * 128 + c] = alj0;
    ws[WS_LJ + (size_t)(n0 + r0 + 1) * 128 + c] = alj1;
}

// swizzled fp16 LDS store into feature buffer
__device__ __forceinline__ void sfw(char* smem, int r, int f, float v) {
    int off = r * SF_STRIDE_B + ((f * 2) ^ ((r & 7) << 4));
    *(_Float16*)(smem + off) = (_Float16)v;
}

// SPLIT=true: ends after LN, writes fp16 pA to global; MLP in mlp_kernel.
// r9 structure exactly; ONLY change: non-temporal pair loads (keep WCT in L2).
template<bool SPLIT>
__global__ __launch_bounds__(256, 4) void main_kernel(
    const float* __restrict__ pair, const float* __restrict__ pos,
    const int* __restrict__ neigh, const int* __restrict__ mask,
    const float* __restrict__ ln_s, const float* __restrict__ ln_b,
    const float* __restrict__ b1, const float* __restrict__ b2,
    const float* __restrict__ ws, const char* __restrict__ wsb,
    _Float16* __restrict__ pa, float* __restrict__ out)
{
    const int R0 = blockIdx.x * ROWS;
    const int tid = threadIdx.x;
    const int lane = tid & 63;
    const int wv = tid >> 6;
    const int myrow = lane & 31;
    const int hi = lane >> 5;
    const int khalf = hi * 8;
    const int swz = (myrow & 7) << 4;

    __shared__ __align__(16) char smem[40960];
    int*   sn  = (int*)(smem + 36864);
    int*   sj  = (int*)(smem + 36992);
    float* spn = (float*)(smem + 37120);   // [32][15]
    float* spj = (float*)(smem + 39040);   // [32][15]

    const _Float16* wct = (const _Float16*)(wsb + WCT_OFF);
    const int colbase = wv * 32 + myrow;

    if (tid < ROWS) {
        int Rg = R0 + tid;
        int n = Rg / K;
        int kk = Rg - n * K;
        int j = neigh[n * K + kk];
        if (j < 0) j += N;
        sn[tid] = n; sj[tid] = j;
    }
    __syncthreads();

    // ---- prefetch pair + li + lj into pv (r9 phase order; pair loads NON-TEMPORAL) ----
    const int nb0 = R0 / K;
    const int nb1 = (nb0 + 1 < N) ? nb0 + 1 : nb0;
    float li0 = ws[WS_LI + (size_t)nb0 * PAIRD + colbase];
    float li1 = ws[WS_LI + (size_t)nb1 * PAIRD + colbase];
    float pv[16];
    #pragma unroll
    for (int q = 0; q < 16; ++q) {
        int rr = (q & 3) + 8 * (q >> 2) + 4 * hi;
        int nq = sn[rr], jq = sj[rr];
        float li = (nq == nb0) ? li0 : li1;
        pv[q] = __builtin_nontemporal_load(&pair[((size_t)nq * N + jq) * PAIRD + colbase])
              + ws[WS_LJ + (size_t)jq * PAIRD + colbase] + li;
    }

    for (int t = tid; t < ROWS * 15; t += 256) {
        int r = t / 15, q = t % 15;
        spn[t] = pos[(size_t)sn[r] * 15 + q];
        spj[t] = pos[(size_t)sj[r] * 15 + q];
    }
    __syncthreads();

    // ===== feature generation: 8 threads per row (r9 exact) =====
    {
        const int fr  = tid >> 3;
        const int sub = tid & 7;
        const float* Pn = spn + fr * 15;
        const float* Pj = spj + fr * 15;

        sfw(smem, fr, 514 + sub, 0.0f);
        sfw(smem, fr, 522 + sub, 0.0f);
        sfw(smem, fr, 530 + sub, 0.0f);
        if (sub < 6) sfw(smem, fr, 538 + sub, 0.0f);

        float rn[9];
        frame_from(Pn, rn);

        #pragma unroll
        for (int m = 0; m < 4; ++m) {
            int ab = sub + 8 * m;
            if (ab < 25) {
                int a = ab / 5, b = ab - 5 * (ab / 5);
                float o0 = Pn[a * 3 + 0] - Pj[b * 3 + 0];
                float o1 = Pn[a * 3 + 1] - Pj[b * 3 + 1];
                float o2 = Pn[a * 3 + 2] - Pj[b * 3 + 2];
                float d = sqrtf(o0 * o0 + o1 * o1 + o2 * o2 + 1e-8f);
                float z = d * (16.0f / 22.0f);
                int base = a * 80 + b * 16;
                int rb = fr * SF_STRIDE_B;
                int rsw = (fr & 7) << 4;
                #pragma unroll
                for (int bp = 0; bp < 8; ++bp) {
                    float e0 = __expf(-z * z);
                    float z1 = z - 1.0666666666666667f;
                    float e1 = __expf(-z1 * z1);
                    z = z1 - 1.0666666666666667f;
                    union { _Float16 h[2]; unsigned u; } pk;
                    pk.h[0] = (_Float16)e0; pk.h[1] = (_Float16)e1;
                    int off = rb + (((base + bp * 2) * 2) ^ rsw);
                    *(unsigned*)(smem + off) = pk.u;
                }
                float l0 = rn[0] * o0 + rn[3] * o1 + rn[6] * o2;
                float l1 = rn[1] * o0 + rn[4] * o1 + rn[7] * o2;
                float l2 = rn[2] * o0 + rn[5] * o1 + rn[8] * o2;
                float inv = rsqrtf(l0 * l0 + l1 * l1 + l2 * l2 + 1e-8f);
                int dbase = 400 + a * 15 + b * 3;
                sfw(smem, fr, dbase + 0, l0 * inv);
                sfw(smem, fr, dbase + 1, l1 * inv);
                sfw(smem, fr, dbase + 2, l2 * inv);
            }
        }

        #pragma unroll
        for (int m = 0; m < 2; ++m) {
            int task = (m == 0) ? sub : (sub < 2 ? 8 + sub : -1);
            if (task >= 0) {
                int a = task >> 1;
                int kind = task & 1;
                const float* Ps = kind ? Pj : Pn;
                float v0 = Ps[a * 3 + 0] - Pn[3];
                float v1 = Ps[a * 3 + 1] - Pn[4];
                float v2 = Ps[a * 3 + 2] - Pn[5];
                float x0 = rn[0] * v0 + rn[3] * v1 + rn[6] * v2;
                float x1 = rn[1] * v0 + rn[4] * v1 + rn[7] * v2;
                float x2 = rn[2] * v0 + rn[5] * v1 + rn[8] * v2;
                int dbase = 484 + a * 6 + kind * 3;
                sfw(smem, fr, dbase + 0, 0.1f * x0);
                sfw(smem, fr, dbase + 1, 0.1f * x1);
                sfw(smem, fr, dbase + 2, 0.1f * x2);
            }
        }

        if (sub == 7) {
            float rj[9];
            frame_from(Pj, rj);
            #pragma unroll
            for (int i = 0; i < 3; ++i)
                #pragma unroll
                for (int jd = 0; jd < 3; ++jd) {
                    float v = rn[0 * 3 + i] * rj[0 * 3 + jd]
                            + rn[1 * 3 + i] * rj[1 * 3 + jd]
                            + rn[2 * 3 + i] * rj[2 * 3 + jd];
                    sfw(smem, fr, 475 + i * 3 + jd, v);
                }
        }
    }
    __syncthreads();

    // ---- GEMM1: feat[32 x 544] @ Wcat[544 x 128]; B streamed ([col][k] layout) ----
    f32x16 acc0, acc1;
    #pragma unroll
    for (int q = 0; q < 16; ++q) { acc0[q] = 0.0f; acc1[q] = 0.0f; }
    {
        const _Float16* wp = wct + (size_t)colbase * FEATK + khalf;
        #pragma unroll
        for (int ks = 0; ks < 34; ks += 2) {
            half8 b0 = *(const half8*)(wp + ks * 16);
            half8 b1 = *(const half8*)(wp + (ks + 1) * 16);
            int k0 = ks * 16 + khalf;
            int k1 = (ks + 1) * 16 + khalf;
            half8 a0 = *(const half8*)(smem + myrow * SF_STRIDE_B + ((k0 * 2) ^ swz));
            half8 a1 = *(const half8*)(smem + myrow * SF_STRIDE_B + ((k1 * 2) ^ swz));
            acc0 = __builtin_amdgcn_mfma_f32_32x32x16_f16(a0, b0, acc0, 0, 0, 0);
            acc1 = __builtin_amdgcn_mfma_f32_32x32x16_f16(a1, b1, acc1, 0, 0, 0);
        }
    }
    __syncthreads();   // sfeat dead; smem[0:16K) becomes pbuf (fp32 [32][128])

    #pragma unroll
    for (int q = 0; q < 16; ++q) {
        int rr = (q & 3) + 8 * (q >> 2) + 4 * hi;
        *(float*)(smem + rr * 512 + colbase * 4) = acc0[q] + acc1[q] + pv[q];
    }
    __syncthreads();

    // ---- LayerNorm (r9 exact) ----
    {
        float lns0 = ln_s[lane], lns1 = ln_s[lane + 64];
        float lnb0 = ln_b[lane], lnb1 = ln_b[lane + 64];
        #pragma unroll
        for (int rr8 = 0; rr8 < 8; ++rr8) {
            int row = wv * 8 + rr8;
            float v0 = *(float*)(smem + row * 512 + lane * 4);
            float v1 = *(float*)(smem + row * 512 + (lane + 64) * 4);
            float s = v0 + v1, s2 = v0 * v0 + v1 * v1;
            #pragma unroll
            for (int o = 32; o > 0; o >>= 1) {
                s += __shfl_xor(s, o, 64);
                s2 += __shfl_xor(s2, o, 64);
            }
            float mu = s * (1.0f / 128.0f);
            float var = s2 * (1.0f / 128.0f) - mu * mu;
            float rs = rsqrtf(var + 1e-5f);
            float y0 = (v0 - mu) * rs * lns0 + lnb0;
            float y1 = (v1 - mu) * rs * lns1 + lnb1;
            if constexpr (SPLIT) {
                pa[(size_t)(R0 + row) * PAIRD + lane]      = (_Float16)y0;
                pa[(size_t)(R0 + row) * PAIRD + lane + 64] = (_Float16)y1;
            } else {
                int sw = (row & 7) << 4;
                *(_Float16*)(smem + 16384 + row * 256 + ((lane * 2) ^ sw)) = (_Float16)y0;
                *(_Float16*)(smem + 16384 + row * 256 + (((lane + 64) * 2) ^ sw)) = (_Float16)y1;
            }
        }
    }
    if constexpr (SPLIT) return;   // MLP + pair_mask handled by mlp_kernel

    __syncthreads();

    // ---- MLP1 (fused mode) ----
    {
        const _Float16* w1t = (const _Float16*)(wsb + W1T_OFF);
        const int c0 = wv * 64 + myrow;
        const int c1 = c0 + 32;
        const _Float16* wp0 = w1t + (size_t)c0 * 128 + khalf;
        const _Float16* wp1 = w1t + (size_t)c1 * 128 + khalf;
        f32x16 h0, h1;
        #pragma unroll
        for (int q = 0; q < 16; ++q) { h0[q] = 0.0f; h1[q] = 0.0f; }
        #pragma unroll
        for (int ks = 0; ks < 8; ++ks) {
            half8 wf0 = *(const half8*)(wp0 + ks * 16);
            half8 wf1 = *(const half8*)(wp1 + ks * 16);
            int k0 = ks * 16 + khalf;
            half8 a = *(const half8*)(smem + 16384 + myrow * 256 + ((k0 * 2) ^ swz));
            h0 = __builtin_amdgcn_mfma_f32_32x32x16_f16(a, wf0, h0, 0, 0, 0);
            h1 = __builtin_amdgcn_mfma_f32_32x32x16_f16(a, wf1, h1, 0, 0, 0);
        }
        float bb0 = b1[c0], bb1 = b1[c1];
        #pragma unroll
        for (int q = 0; q < 16; ++q) {
            int rr = (q & 3) + 8 * (q >> 2) + 4 * hi;
            int sw = (rr & 7) << 4;
            *(_Float16*)(smem + rr * 512 + ((c0 * 2) ^ sw)) = (_Float16)gelu_fast(h0[q] + bb0);
            *(_Float16*)(smem + rr * 512 + ((c1 * 2) ^ sw)) = (_Float16)gelu_fast(h1[q] + bb1);
        }
    }
    __syncthreads();

    // ---- MLP2 (fused mode) ----
    {
        const _Float16* w2t = (const _Float16*)(wsb + W2T_OFF);
        const int oc = wv * 32 + myrow;
        const _Float16* wp = w2t + (size_t)oc * 256 + khalf;
        f32x16 o0, o1;
        #pragma unroll
        for (int q = 0; q < 16; ++q) { o0[q] = 0.0f; o1[q] = 0.0f; }
        #pragma unroll
        for (int ks = 0; ks < 16; ks += 2) {
            half8 w0 = *(const half8*)(wp + ks * 16);
            half8 w1f = *(const half8*)(wp + (ks + 1) * 16);
            int k0 = ks * 16 + khalf;
            int k1 = (ks + 1) * 16 + khalf;
            half8 a0 = *(const half8*)(smem + myrow * 512 + ((k0 * 2) ^ swz));
            half8 a1 = *(const half8*)(smem + myrow * 512 + ((k1 * 2) ^ swz));
            o0 = __builtin_amdgcn_mfma_f32_32x32x16_f16(a0, w0, o0, 0, 0, 0);
            o1 = __builtin_amdgcn_mfma_f32_32x32x16_f16(a1, w1f, o1, 0, 0, 0);
        }
        float bb = b2[oc];
        #pragma unroll
        for (int q = 0; q < 16; ++q) {
            int rr = (q & 3) + 8 * (q >> 2) + 4 * hi;
            __builtin_nontemporal_store(o0[q] + o1[q] + bb,
                &out[((size_t)(R0 + rr)) * PAIRD + oc]);
        }
    }

    if (tid < ROWS) {
        int Rg = R0 + tid;
        int n = Rg / K;
        int kk = Rg - n * K;
        int jr = neigh[n * K + kk];
        int jj = jr < 0 ? jr + N : jr;
        bool pm = (jr != -1) && (mask[n] != 0) && (mask[jj] != 0);
        out[(size_t)N * K * PAIRD + Rg] = pm ? 1.0f : 0.0f;
    }
}

// MLP kernel (split mode): 64 rows/block (r9 exact); out stores non-temporal.
__global__ __launch_bounds__(256, 3) void mlp_kernel(
    const _Float16* __restrict__ pa, const int* __restrict__ neigh,
    const int* __restrict__ mask, const float* __restrict__ b1,
    const float* __restrict__ b2, const char* __restrict__ wsb,
    float* __restrict__ out)
{
    const int R0 = blockIdx.x * 64;
    const int tid = threadIdx.x;
    const int lane = tid & 63;
    const int wv = tid >> 6;
    const int myrow = lane & 31;
    const int hi = lane >> 5;
    const int khalf = hi * 8;
    const int swz = (myrow & 7) << 4;

    __shared__ __align__(16) char smem[49152];  // pA [64][256B] @0, hbuf [64][512B] @16384

    for (int ch = tid; ch < 1024; ch += 256) {
        int row = ch >> 4, c16 = ch & 15;
        half8 v = *(const half8*)(pa + (size_t)(R0 + row) * PAIRD + c16 * 8);
        *(half8*)(smem + row * 256 + ((c16 * 16) ^ ((row & 7) << 4))) = v;
    }
    __syncthreads();

    {
        const _Float16* w1t = (const _Float16*)(wsb + W1T_OFF);
        const int c0 = wv * 64 + myrow;
        const int c1 = c0 + 32;
        const _Float16* wp0 = w1t + (size_t)c0 * 128 + khalf;
        const _Float16* wp1 = w1t + (size_t)c1 * 128 + khalf;
        f32x16 h00, h01, h10, h11;
        #pragma unroll
        for (int q = 0; q < 16; ++q) { h00[q] = 0.0f; h01[q] = 0.0f; h10[q] = 0.0f; h11[q] = 0.0f; }
        #pragma unroll
        for (int ks = 0; ks < 8; ++ks) {
            int k0 = ks * 16 + khalf;
            half8 wf0 = *(const half8*)(wp0 + ks * 16);
            half8 wf1 = *(const half8*)(wp1 + ks * 16);
            half8 a0 = *(const half8*)(smem + myrow * 256 + ((k0 * 2) ^ swz));
            half8 a1 = *(const half8*)(smem + (32 + myrow) * 256 + ((k0 * 2) ^ swz));
            h00 = __builtin_amdgcn_mfma_f32_32x32x16_f16(a0, wf0, h00, 0, 0, 0);
            h01 = __builtin_amdgcn_mfma_f32_32x32x16_f16(a0, wf1, h01, 0, 0, 0);
            h10 = __builtin_amdgcn_mfma_f32_32x32x16_f16(a1, wf0, h10, 0, 0, 0);
            h11 = __builtin_amdgcn_mfma_f32_32x32x16_f16(a1, wf1, h11, 0, 0, 0);
        }
        float bb0 = b1[c0], bb1 = b1[c1];
        #pragma unroll
        for (int q = 0; q < 16; ++q) {
            int rr = (q & 3) + 8 * (q >> 2) + 4 * hi;
            int sw = (rr & 7) << 4;
            *(_Float16*)(smem + 16384 + rr * 512 + ((c0 * 2) ^ sw)) = (_Float16)gelu_fast(h00[q] + bb0);
            *(_Float16*)(smem + 16384 + rr * 512 + ((c1 * 2) ^ sw)) = (_Float16)gelu_fast(h01[q] + bb1);
            *(_Float16*)(smem + 16384 + (rr + 32) * 512 + ((c0 * 2) ^ sw)) = (_Float16)gelu_fast(h10[q] + bb0);
            *(_Float16*)(smem + 16384 + (rr + 32) * 512 + ((c1 * 2) ^ sw)) = (_Float16)gelu_fast(h11[q] + bb1);
        }
    }
    __syncthreads();

    {
        const _Float16* w2t = (const _Float16*)(wsb + W2T_OFF);
        const int oc = wv * 32 + myrow;
        const _Float16* wp = w2t + (size_t)oc * 256 + khalf;
        f32x16 o0, o1;
        #pragma unroll
        for (int q = 0; q < 16; ++q) { o0[q] = 0.0f; o1[q] = 0.0f; }
        #pragma unroll
        for (int ks = 0; ks < 16; ++ks) {
            int k0 = ks * 16 + khalf;
            half8 wf = *(const half8*)(wp + ks * 16);
            half8 a0 = *(const half8*)(smem + 16384 + myrow * 512 + ((k0 * 2) ^ swz));
            half8 a1 = *(const half8*)(smem + 16384 + (32 + myrow) * 512 + ((k0 * 2) ^ swz));
            o0 = __builtin_amdgcn_mfma_f32_32x32x16_f16(a0, wf, o0, 0, 0, 0);
            o1 = __builtin_amdgcn_mfma_f32_32x32x16_f16(a1, wf, o1, 0, 0, 0);
        }
        float bb = b2[oc];
        #pragma unroll
        for (int q = 0; q < 16; ++q) {
            int rr = (q & 3) + 8 * (q >> 2) + 4 * hi;
            __builtin_nontemporal_store(o0[q] + bb, &out[((size_t)(R0 + rr)) * PAIRD + oc]);
            __builtin_nontemporal_store(o1[q] + bb, &out[((size_t)(R0 + rr + 32)) * PAIRD + oc]);
        }
    }

    if (tid < 64) {
        int Rg = R0 + tid;
        int n = Rg / K;
        int kk = Rg - n * K;
        int jr = neigh[n * K + kk];
        int jj = jr < 0 ? jr + N : jr;
        bool pm = (jr != -1) && (mask[n] != 0) && (mask[jj] != 0);
        out[(size_t)N * K * PAIRD + Rg] = pm ? 1.0f : 0.0f;
    }
}

extern "C" void kernel_launch(void* const* d_in, const int* in_sizes, int n_in,
                              void* d_out, int out_size, void* d_ws, size_t ws_size,
                              hipStream_t stream) {
    const float* local_ = (const float*)d_in[0];
    const float* pos = (const float*)d_in[1];
    const float* pair = (const float*)d_in[2];
    const int* neigh = (const int*)d_in[3];
    const int* mask = (const int*)d_in[4];
    const float* W_li = (const float*)d_in[5];
    const float* W_lj = (const float*)d_in[6];
    const float* W_dist = (const float*)d_in[7];
    const float* W_dir = (const float*)d_in[8];
    const float* W_rot = (const float*)d_in[9];
    const float* W_vec = (const float*)d_in[10];
    const float* ln_s = (const float*)d_in[11];
    const float* ln_b = (const float*)d_in[12];
    const float* w1 = (const float*)d_in[13];
    const float* b1 = (const float*)d_in[14];
    const float* w2 = (const float*)d_in[15];
    const float* b2 = (const float*)d_in[16];
    float* ws = (float*)d_ws;
    char* wsb = (char*)d_ws;
    _Float16* pa = (_Float16*)(wsb + PA_OFF);
    float* out = (float*)d_out;

    hipLaunchKernelGGL(prep_kernel, dim3(256 + 528), dim3(256), 0, stream,
                       local_, W_li, W_lj, W_dist, W_dir, W_rot, W_vec,
                       w1, w2, ws, wsb);
    if (ws_size >= WS_NEEDED) {
        main_kernel<true><<<dim3((N * K) / ROWS), dim3(256), 0, stream>>>(
            pair, pos, neigh, mask, ln_s, ln_b, b1, b2, ws, wsb, pa, out);
        mlp_kernel<<<dim3((N * K) / 64), dim3(256), 0, stream>>>(
            pa, neigh, mask, b1, b2, wsb, out);
    } else {
        main_kernel<false><<<dim3((N * K) / ROWS), dim3(256), 0, stream>>>(
            pair, pos, neigh, mask, ln_s, ln_b, b1, b2, ws, wsb, pa, out);
    }
}